// Round 8
// baseline (34.274 us; speedup 1.0000x reference)
//
#include <hip/hip_runtime.h>
#include <math.h>

namespace {

constexpr int kD = 1024;
constexpr int kL = 1024;
constexpr int kN = 16;
constexpr int kE = 8;    // l-steps per thread
constexpr int kJ = 8;    // n-states per thread
constexpr int kT = 256;  // threads per block; block = one (b,d)

__global__ __launch_bounds__(kT)
void selscan(const float* __restrict__ u,
             const float* __restrict__ delta,
             const float* __restrict__ A,
             const float* __restrict__ Bm,
             const float* __restrict__ Cm,
             const float* __restrict__ Dv,
             const float* __restrict__ z,
             float* __restrict__ out)
{
    // chunk summaries (a,x) per [chunk][n]; +1 float2 pad per row.
    // After the scanner pass, .x of each slot holds the exclusive carry.
    __shared__ float2 sax[128][kN + 1];   // 17408 B

    const int bd   = blockIdx.x;
    const int b    = bd >> 10;          // kD = 1024
    const int d    = bd & (kD - 1);
    const int t    = threadIdx.x;
    const int lane = t & 63;
    const int wave = t >> 6;
    const int nh   = t & 1;             // which half of n
    const int n0   = nh << 3;
    const int chunk = t >> 1;           // 0..127
    const int l0   = chunk << 3;        // 8 elements per chunk
    const size_t base = (size_t)bd * kL;
    const int eoff = l0 + nh * 4;       // epilogue element offset (== 4*t)

    const float LOG2E = 1.4426950408889634f;
    const float LN2   = 0.6931471805599453f;

    // ---- Early loads: delta, u, z (z held in regs until epilogue) ----
    float4 d0 = *(const float4*)(delta + base + l0);
    float4 d1 = *(const float4*)(delta + base + l0 + 4);
    float4 u0 = *(const float4*)(u + base + l0);
    float4 u1 = *(const float4*)(u + base + l0 + 4);
    float4 zv = *(const float4*)(z + base + eoff);

    // ---- A row, pre-scaled by log2(e) for exp2 ----
    float cj[kJ];
    {
        float4 a0 = *(const float4*)(A + d * kN + n0);
        float4 a1 = *(const float4*)(A + d * kN + n0 + 4);
        cj[0]=a0.x*LOG2E; cj[1]=a0.y*LOG2E; cj[2]=a0.z*LOG2E; cj[3]=a0.w*LOG2E;
        cj[4]=a1.x*LOG2E; cj[5]=a1.y*LOG2E; cj[6]=a1.z*LOG2E; cj[7]=a1.w*LOG2E;
    }

    // ---- Prefetch B/C row j=0 ----
    const int rowbase = (b << 4) + n0;
    const float* Bp = Bm + (size_t)rowbase * kL + l0;
    const float* Cp = Cm + (size_t)rowbase * kL + l0;
    float4 pb0 = *(const float4*)Bp;
    float4 pb1 = *(const float4*)(Bp + 4);
    float4 pc0 = *(const float4*)Cp;
    float4 pc1 = *(const float4*)(Cp + 4);

    // ---- dt = softplus(delta), dtu = dt*u (overlaps B/C j=0 latency) ----
    float dt[kE], dtu[kE];
    {
        float dd[kE] = {d0.x,d0.y,d0.z,d0.w,d1.x,d1.y,d1.z,d1.w};
        float uu[kE] = {u0.x,u0.y,u0.z,u0.w,u1.x,u1.y,u1.z,u1.w};
        #pragma unroll
        for (int s = 0; s < kE; ++s) {
            float x = dd[s];
            float e = __builtin_amdgcn_exp2f(-fabsf(x) * LOG2E);
            float sp = fmaxf(x, 0.f) + __builtin_amdgcn_logf(1.f + e) * LN2;
            dt[s]  = sp;
            dtu[s] = sp * uu[s];
        }
    }

    // ---- Phase 1: local scan with 1-deep pipelined B/C loads ----
    float Q[kJ][kE];
    float y[kE] = {0.f,0.f,0.f,0.f,0.f,0.f,0.f,0.f};
    #pragma unroll
    for (int j = 0; j < kJ; ++j) {
        // consume current prefetch
        float Bv[kE] = {pb0.x,pb0.y,pb0.z,pb0.w,pb1.x,pb1.y,pb1.z,pb1.w};
        float Cv[kE] = {pc0.x,pc0.y,pc0.z,pc0.w,pc1.x,pc1.y,pc1.z,pc1.w};
        // issue next row's loads before computing
        if (j < kJ - 1) {
            const float* Bn = Bm + (size_t)(rowbase + j + 1) * kL + l0;
            const float* Cn = Cm + (size_t)(rowbase + j + 1) * kL + l0;
            pb0 = *(const float4*)Bn;
            pb1 = *(const float4*)(Bn + 4);
            pc0 = *(const float4*)Cn;
            pc1 = *(const float4*)(Cn + 4);
        }
        float x = 0.f, p = 1.f;
        #pragma unroll
        for (int s = 0; s < kE; ++s) {
            float e = __builtin_amdgcn_exp2f(dt[s] * cj[j]);
            x = fmaf(e, x, dtu[s] * Bv[s]);
            p *= e;
            Q[j][s] = p * Cv[s];
            y[s] = fmaf(x, Cv[s], y[s]);
        }
        sax[chunk][n0 + j] = make_float2(p, x);
    }
    __syncthreads();

    // ---- Scanner: wave 0 computes exclusive carries for all 128 chunks ----
    if (wave == 0) {
        const int sn = lane & 15;       // state n
        const int q  = lane >> 4;       // chunk group (32 chunks each)
        const int cb = q << 5;
        float p = 1.f, c = 0.f;
        #pragma unroll 8
        for (int i = 0; i < 32; ++i) {
            float2 ax = sax[cb + i][sn];
            c = fmaf(ax.x, c, ax.y);
            p *= ax.x;
        }
        float Ag = p, Xg = c;
        {
            float ain = __shfl_up(Ag, 16, 64);
            float xin = __shfl_up(Xg, 16, 64);
            bool act = (lane >= 16);
            Xg = fmaf(Ag, act ? xin : 0.f, Xg);
            Ag *= act ? ain : 1.f;
            ain = __shfl_up(Ag, 32, 64);
            xin = __shfl_up(Xg, 32, 64);
            act = (lane >= 32);
            Xg = fmaf(Ag, act ? xin : 0.f, Xg);
            Ag *= act ? ain : 1.f;
        }
        float gx = __shfl_up(Xg, 16, 64);
        float cc = (lane >= 16) ? gx : 0.f;
        #pragma unroll 8
        for (int i = 0; i < 32; ++i) {
            float2 ax = sax[cb + i][sn];
            sax[cb + i][sn].x = cc;
            cc = fmaf(ax.x, cc, ax.y);
        }
    }
    __syncthreads();

    // ---- Phase 2: y += carry_j * Q_j (carries straight from LDS) ----
    #pragma unroll
    for (int j = 0; j < kJ; ++j) {
        float carry = sax[chunk][n0 + j].x;
        #pragma unroll
        for (int s = 0; s < kE; ++s)
            y[s] = fmaf(carry, Q[j][s], y[s]);
    }

    // ---- Combine the two n-halves (lane pairs) ----
    #pragma unroll
    for (int s = 0; s < kE; ++s) y[s] += __shfl_xor(y[s], 1, 64);

    // ---- Epilogue: reuse u regs; z preloaded; constant-index selects ----
    const float D_d = Dv[d];
    float y0 = nh ? y[4] : y[0];
    float y1 = nh ? y[5] : y[1];
    float y2 = nh ? y[6] : y[2];
    float y3 = nh ? y[7] : y[3];
    float ue0 = nh ? u1.x : u0.x;
    float ue1 = nh ? u1.y : u0.y;
    float ue2 = nh ? u1.z : u0.z;
    float ue3 = nh ? u1.w : u0.w;

    float s0 = __builtin_amdgcn_rcpf(1.f + __builtin_amdgcn_exp2f(-zv.x * LOG2E));
    float s1 = __builtin_amdgcn_rcpf(1.f + __builtin_amdgcn_exp2f(-zv.y * LOG2E));
    float s2 = __builtin_amdgcn_rcpf(1.f + __builtin_amdgcn_exp2f(-zv.z * LOG2E));
    float s3 = __builtin_amdgcn_rcpf(1.f + __builtin_amdgcn_exp2f(-zv.w * LOG2E));
    float4 o;
    o.x = (y0 + ue0 * D_d) * zv.x * s0;
    o.y = (y1 + ue1 * D_d) * zv.y * s1;
    o.z = (y2 + ue2 * D_d) * zv.z * s2;
    o.w = (y3 + ue3 * D_d) * zv.w * s3;
    *(float4*)(out + base + eoff) = o;
}

}  // namespace

extern "C" void kernel_launch(void* const* d_in, const int* in_sizes, int n_in,
                              void* d_out, int out_size, void* d_ws, size_t ws_size,
                              hipStream_t stream) {
    const float* u     = (const float*)d_in[0];
    const float* delta = (const float*)d_in[1];
    const float* A     = (const float*)d_in[2];
    const float* Bm    = (const float*)d_in[3];
    const float* Cm    = (const float*)d_in[4];
    const float* Dv    = (const float*)d_in[5];
    const float* z     = (const float*)d_in[6];
    float* out = (float*)d_out;

    dim3 grid(2 * kD);
    dim3 block(kT);
    hipLaunchKernelGGL(selscan, grid, block, 0, stream,
                       u, delta, A, Bm, Cm, Dv, z, out);
}